// Round 2
// baseline (211.725 us; speedup 1.0000x reference)
//
#include <hip/hip_runtime.h>
#include <cstddef>

#define BSZ  1024
#define TT   128
#define LAB  64
#define DEMO 16
#define HID  32
#define FF   4

__device__ __forceinline__ float fast_sigmoid(float x) {
    return 1.0f / (1.0f + __expf(-x));
}
__device__ __forceinline__ float fast_tanh(float x) {
    // tanh(x) = 1 - 2/(exp(2x)+1); saturates correctly at +/-inf
    return 1.0f - 2.0f / (__expf(2.0f * x) + 1.0f);
}

__global__ __launch_bounds__(64, 1)
void mcgru_fused(const float* __restrict__ x,
                 const float* __restrict__ stat,
                 const float* __restrict__ demo_W,
                 const float* __restrict__ demo_b,
                 const float* __restrict__ lab_W,
                 const float* __restrict__ lab_b,
                 const float* __restrict__ Wih,
                 const float* __restrict__ bih,
                 const float* __restrict__ Whh,
                 const float* __restrict__ bhh,
                 const float* __restrict__ out_W,
                 const float* __restrict__ out_b,
                 float* __restrict__ out)
{
    const int b = blockIdx.x;
    const int l = threadIdx.x;   // 0..63, one lab-GRU chain per thread
    if (b >= BSZ) return;

    // ---- per-thread (per-lab) weights into VGPRs ----
    float wl[LAB];                       // lab_W row l
    #pragma unroll
    for (int k = 0; k < LAB; k += 4) {
        float4 v = *reinterpret_cast<const float4*>(lab_W + l * LAB + k);
        wl[k] = v.x; wl[k+1] = v.y; wl[k+2] = v.z; wl[k+3] = v.w;
    }
    float whh[3 * FF * FF];              // Whh[l]: [12][4] row-major, 48 floats
    #pragma unroll
    for (int k = 0; k < 48; k += 4) {
        float4 v = *reinterpret_cast<const float4*>(Whh + l * 48 + k);
        whh[k] = v.x; whh[k+1] = v.y; whh[k+2] = v.z; whh[k+3] = v.w;
    }
    float wih[12], bihv[12], bhhv[12];
    #pragma unroll
    for (int k = 0; k < 12; k += 4) {
        float4 a = *reinterpret_cast<const float4*>(Wih + l * 12 + k);
        float4 c = *reinterpret_cast<const float4*>(bih + l * 12 + k);
        float4 d = *reinterpret_cast<const float4*>(bhh + l * 12 + k);
        wih[k] = a.x; wih[k+1] = a.y; wih[k+2] = a.z; wih[k+3] = a.w;
        bihv[k] = c.x; bihv[k+1] = c.y; bihv[k+2] = c.z; bihv[k+3] = c.w;
        bhhv[k] = d.x; bhhv[k+1] = d.y; bhhv[k+2] = d.z; bhhv[k+3] = d.w;
    }
    // fold biases for r/z gates: pre = xt*Wih + (bih+bhh) + h.Whh
    float bc[8];
    #pragma unroll
    for (int g = 0; g < 8; ++g) bc[g] = bihv[g] + bhhv[g];
    const float lb = lab_b[l];

    float h0 = 0.f, h1 = 0.f, h2 = 0.f, h3 = 0.f;

    const float* xrow = x + (size_t)b * TT * LAB;

    for (int t = 0; t < TT; ++t) {
        // ---- xt = lab_b[l] + dot(x[b,t,:], lab_W[l,:])  (x row is wave-uniform) ----
        const float4* xr4 = reinterpret_cast<const float4*>(xrow + t * LAB);
        float a0 = 0.f, a1 = 0.f, a2 = 0.f, a3 = 0.f;
        #pragma unroll
        for (int k = 0; k < LAB / 4; ++k) {
            float4 v = xr4[k];           // uniform address -> expect s_load
            a0 = fmaf(v.x, wl[4*k + 0], a0);
            a1 = fmaf(v.y, wl[4*k + 1], a1);
            a2 = fmaf(v.z, wl[4*k + 2], a2);
            a3 = fmaf(v.w, wl[4*k + 3], a3);
        }
        const float xt = lb + ((a0 + a1) + (a2 + a3));

        // ---- GRU gates ----
        float pre[8];
        #pragma unroll
        for (int g = 0; g < 8; ++g) {
            float acc = fmaf(xt, wih[g], bc[g]);
            acc = fmaf(h0, whh[g*4 + 0], acc);
            acc = fmaf(h1, whh[g*4 + 1], acc);
            acc = fmaf(h2, whh[g*4 + 2], acc);
            acc = fmaf(h3, whh[g*4 + 3], acc);
            pre[g] = acc;
        }
        float r0 = fast_sigmoid(pre[0]);
        float r1 = fast_sigmoid(pre[1]);
        float r2 = fast_sigmoid(pre[2]);
        float r3 = fast_sigmoid(pre[3]);
        float z0 = fast_sigmoid(pre[4]);
        float z1 = fast_sigmoid(pre[5]);
        float z2 = fast_sigmoid(pre[6]);
        float z3 = fast_sigmoid(pre[7]);

        float ghn[4], gin[4];
        #pragma unroll
        for (int i = 0; i < 4; ++i) {
            int g = 8 + i;
            float acc = bhhv[g];
            acc = fmaf(h0, whh[g*4 + 0], acc);
            acc = fmaf(h1, whh[g*4 + 1], acc);
            acc = fmaf(h2, whh[g*4 + 2], acc);
            acc = fmaf(h3, whh[g*4 + 3], acc);
            ghn[i] = acc;
            gin[i] = fmaf(xt, wih[g], bihv[g]);
        }
        float n0 = fast_tanh(fmaf(r0, ghn[0], gin[0]));
        float n1 = fast_tanh(fmaf(r1, ghn[1], gin[1]));
        float n2 = fast_tanh(fmaf(r2, ghn[2], gin[2]));
        float n3 = fast_tanh(fmaf(r3, ghn[3], gin[3]));

        // h = n + z*(h - n)
        h0 = fmaf(z0, h0 - n0, n0);
        h1 = fmaf(z1, h1 - n1, n1);
        h2 = fmaf(z2, h2 - n2, n2);
        h3 = fmaf(z3, h3 - n3, n3);
    }

    // ---- epilogue: cat = [demo(32) | feat(256)] in LDS, then out = cat @ out_W.T + out_b
    __shared__ float cat[HID + LAB * FF];   // 288 floats
    cat[HID + l*4 + 0] = h0;
    cat[HID + l*4 + 1] = h1;
    cat[HID + l*4 + 2] = h2;
    cat[HID + l*4 + 3] = h3;
    if (l < HID) {
        float acc = demo_b[l];
        const float* sr = stat + (size_t)b * DEMO;      // wave-uniform
        const float* dwr = demo_W + l * DEMO;
        #pragma unroll
        for (int d = 0; d < DEMO; ++d)
            acc = fmaf(sr[d], dwr[d], acc);
        cat[l] = acc;
    }
    __syncthreads();

    if (l < HID) {
        float acc = out_b[l];
        const float* wrow = out_W + l * (HID + LAB * FF);
        #pragma unroll
        for (int i = 0; i < HID + LAB * FF; i += 4) {
            float4 wv = *reinterpret_cast<const float4*>(wrow + i);
            acc = fmaf(cat[i + 0], wv.x, acc);
            acc = fmaf(cat[i + 1], wv.y, acc);
            acc = fmaf(cat[i + 2], wv.z, acc);
            acc = fmaf(cat[i + 3], wv.w, acc);
        }
        out[(size_t)b * HID + l] = acc;
    }
}

extern "C" void kernel_launch(void* const* d_in, const int* in_sizes, int n_in,
                              void* d_out, int out_size, void* d_ws, size_t ws_size,
                              hipStream_t stream) {
    const float* x      = (const float*)d_in[0];
    const float* stat   = (const float*)d_in[1];
    const float* demo_W = (const float*)d_in[2];
    const float* demo_b = (const float*)d_in[3];
    const float* lab_W  = (const float*)d_in[4];
    const float* lab_b  = (const float*)d_in[5];
    const float* Wih    = (const float*)d_in[6];
    const float* bih    = (const float*)d_in[7];
    const float* Whh    = (const float*)d_in[8];
    const float* bhh    = (const float*)d_in[9];
    const float* out_W  = (const float*)d_in[10];
    const float* out_b  = (const float*)d_in[11];
    float* out = (float*)d_out;

    dim3 grid(BSZ);
    dim3 block(LAB);
    hipLaunchKernelGGL(mcgru_fused, grid, block, 0, stream,
                       x, stat, demo_W, demo_b, lab_W, lab_b,
                       Wih, bih, Whh, bhh, out_W, out_b, out);
}

// Round 3
// 204.097 us; speedup vs baseline: 1.0374x; 1.0374x over previous
//
#include <hip/hip_runtime.h>
#include <cstddef>

#define BSZ   1024
#define TT    128
#define LAB   64
#define DEMO  16
#define HID   32
#define FF    4
#define CHUNK 32
#define NCHUNK (TT / CHUNK)

__device__ __forceinline__ float fast_sigmoid(float x) {
    return 1.0f / (1.0f + __expf(-x));
}
__device__ __forceinline__ float fast_tanh(float x) {
    return 1.0f - 2.0f / (__expf(2.0f * x) + 1.0f);
}

__global__ __launch_bounds__(64, 1)
void mcgru_fused(const float* __restrict__ x,
                 const float* __restrict__ stat,
                 const float* __restrict__ demo_W,
                 const float* __restrict__ demo_b,
                 const float* __restrict__ lab_W,
                 const float* __restrict__ lab_b,
                 const float* __restrict__ Wih,
                 const float* __restrict__ bih,
                 const float* __restrict__ Whh,
                 const float* __restrict__ bhh,
                 const float* __restrict__ out_W,
                 const float* __restrict__ out_b,
                 float* __restrict__ out)
{
    const int b = blockIdx.x;
    const int l = threadIdx.x;   // one lab-chain per lane; block = 1 wave

    __shared__ float xs[CHUNK * LAB];        // 8 KB staged x rows
    __shared__ float xp[CHUNK * LAB];        // 8 KB projected xt values
    __shared__ float cat[HID + LAB * FF];    // epilogue concat

    // ---- per-lane (per-lab) weights into VGPRs ----
    float wl[LAB];
    #pragma unroll
    for (int k = 0; k < LAB; k += 4) {
        float4 v = *reinterpret_cast<const float4*>(lab_W + l * LAB + k);
        wl[k] = v.x; wl[k+1] = v.y; wl[k+2] = v.z; wl[k+3] = v.w;
    }
    float whh[3 * FF * FF];
    #pragma unroll
    for (int k = 0; k < 48; k += 4) {
        float4 v = *reinterpret_cast<const float4*>(Whh + l * 48 + k);
        whh[k] = v.x; whh[k+1] = v.y; whh[k+2] = v.z; whh[k+3] = v.w;
    }
    float wih[12], bihv[12], bhhv[12];
    #pragma unroll
    for (int k = 0; k < 12; k += 4) {
        float4 a = *reinterpret_cast<const float4*>(Wih + l * 12 + k);
        float4 c = *reinterpret_cast<const float4*>(bih + l * 12 + k);
        float4 d = *reinterpret_cast<const float4*>(bhh + l * 12 + k);
        wih[k] = a.x; wih[k+1] = a.y; wih[k+2] = a.z; wih[k+3] = a.w;
        bihv[k] = c.x; bihv[k+1] = c.y; bihv[k+2] = c.z; bihv[k+3] = c.w;
        bhhv[k] = d.x; bhhv[k+1] = d.y; bhhv[k+2] = d.z; bhhv[k+3] = d.w;
    }
    float bc[8];
    #pragma unroll
    for (int g = 0; g < 8; ++g) bc[g] = bihv[g] + bhhv[g];
    const float lb = lab_b[l];

    float h0 = 0.f, h1 = 0.f, h2 = 0.f, h3 = 0.f;

    const float4* xrow4 = reinterpret_cast<const float4*>(x + (size_t)b * TT * LAB);

    for (int c = 0; c < NCHUNK; ++c) {
        // ---- phase 1: stage 32 rows of x (8 KB), coalesced, independent loads ----
        const float4* src = xrow4 + c * (CHUNK * LAB / 4);
        #pragma unroll
        for (int i = 0; i < 8; ++i) {
            float4 v = src[i * 64 + l];
            *reinterpret_cast<float4*>(&xs[(i * 64 + l) * 4]) = v;
        }
        __syncthreads();

        // ---- phase 2: xp[t][l] = lab_b[l] + dot(xs[t], lab_W[l]) — 32 independent dots
        #pragma unroll 2
        for (int t = 0; t < CHUNK; ++t) {
            const float4* row = reinterpret_cast<const float4*>(&xs[t * LAB]); // uniform -> broadcast
            float a0 = 0.f, a1 = 0.f, a2 = 0.f, a3 = 0.f;
            #pragma unroll
            for (int k = 0; k < LAB / 4; ++k) {
                float4 v = row[k];
                a0 = fmaf(v.x, wl[4*k + 0], a0);
                a1 = fmaf(v.y, wl[4*k + 1], a1);
                a2 = fmaf(v.z, wl[4*k + 2], a2);
                a3 = fmaf(v.w, wl[4*k + 3], a3);
            }
            xp[t * LAB + l] = lb + ((a0 + a1) + (a2 + a3));
        }

        // ---- phase 3: 32 GRU steps; xt from LDS (own element, conflict-free) ----
        for (int t = 0; t < CHUNK; ++t) {
            const float xt = xp[t * LAB + l];

            float pre[8];
            #pragma unroll
            for (int g = 0; g < 8; ++g) {
                float acc = fmaf(xt, wih[g], bc[g]);
                acc = fmaf(h0, whh[g*4 + 0], acc);
                acc = fmaf(h1, whh[g*4 + 1], acc);
                acc = fmaf(h2, whh[g*4 + 2], acc);
                acc = fmaf(h3, whh[g*4 + 3], acc);
                pre[g] = acc;
            }
            float r0 = fast_sigmoid(pre[0]);
            float r1 = fast_sigmoid(pre[1]);
            float r2 = fast_sigmoid(pre[2]);
            float r3 = fast_sigmoid(pre[3]);
            float z0 = fast_sigmoid(pre[4]);
            float z1 = fast_sigmoid(pre[5]);
            float z2 = fast_sigmoid(pre[6]);
            float z3 = fast_sigmoid(pre[7]);

            float ghn[4], gin[4];
            #pragma unroll
            for (int i = 0; i < 4; ++i) {
                int g = 8 + i;
                float acc = bhhv[g];
                acc = fmaf(h0, whh[g*4 + 0], acc);
                acc = fmaf(h1, whh[g*4 + 1], acc);
                acc = fmaf(h2, whh[g*4 + 2], acc);
                acc = fmaf(h3, whh[g*4 + 3], acc);
                ghn[i] = acc;
                gin[i] = fmaf(xt, wih[g], bihv[g]);
            }
            float n0 = fast_tanh(fmaf(r0, ghn[0], gin[0]));
            float n1 = fast_tanh(fmaf(r1, ghn[1], gin[1]));
            float n2 = fast_tanh(fmaf(r2, ghn[2], gin[2]));
            float n3 = fast_tanh(fmaf(r3, ghn[3], gin[3]));

            h0 = fmaf(z0, h0 - n0, n0);
            h1 = fmaf(z1, h1 - n1, n1);
            h2 = fmaf(z2, h2 - n2, n2);
            h3 = fmaf(z3, h3 - n3, n3);
        }
        __syncthreads();   // protect xs before next chunk's staging overwrite
    }

    // ---- epilogue ----
    cat[HID + l*4 + 0] = h0;
    cat[HID + l*4 + 1] = h1;
    cat[HID + l*4 + 2] = h2;
    cat[HID + l*4 + 3] = h3;
    if (l < HID) {
        float acc = demo_b[l];
        const float* sr = stat + (size_t)b * DEMO;
        const float* dwr = demo_W + l * DEMO;
        #pragma unroll
        for (int d = 0; d < DEMO; ++d)
            acc = fmaf(sr[d], dwr[d], acc);
        cat[l] = acc;
    }
    __syncthreads();

    if (l < HID) {
        float acc = out_b[l];
        const float* wrow = out_W + l * (HID + LAB * FF);
        #pragma unroll
        for (int i = 0; i < HID + LAB * FF; i += 4) {
            float4 wv = *reinterpret_cast<const float4*>(wrow + i);
            acc = fmaf(cat[i + 0], wv.x, acc);
            acc = fmaf(cat[i + 1], wv.y, acc);
            acc = fmaf(cat[i + 2], wv.z, acc);
            acc = fmaf(cat[i + 3], wv.w, acc);
        }
        out[(size_t)b * HID + l] = acc;
    }
}

extern "C" void kernel_launch(void* const* d_in, const int* in_sizes, int n_in,
                              void* d_out, int out_size, void* d_ws, size_t ws_size,
                              hipStream_t stream) {
    const float* x      = (const float*)d_in[0];
    const float* stat   = (const float*)d_in[1];
    const float* demo_W = (const float*)d_in[2];
    const float* demo_b = (const float*)d_in[3];
    const float* lab_W  = (const float*)d_in[4];
    const float* lab_b  = (const float*)d_in[5];
    const float* Wih    = (const float*)d_in[6];
    const float* bih    = (const float*)d_in[7];
    const float* Whh    = (const float*)d_in[8];
    const float* bhh    = (const float*)d_in[9];
    const float* out_W  = (const float*)d_in[10];
    const float* out_b  = (const float*)d_in[11];
    float* out = (float*)d_out;

    dim3 grid(BSZ);
    dim3 block(LAB);
    hipLaunchKernelGGL(mcgru_fused, grid, block, 0, stream,
                       x, stat, demo_W, demo_b, lab_W, lab_b,
                       Wih, bih, Whh, bhh, out_W, out_b, out);
}

// Round 5
// 168.083 us; speedup vs baseline: 1.2596x; 1.2143x over previous
//
#include <hip/hip_runtime.h>
#include <cstddef>

#define BSZ   1024
#define TT    128
#define LAB   64
#define DEMO  16
#define HID   32
#define FF    4
#define CHUNK 32
#define NCHUNK (TT / CHUNK)

// sigmoid(pre) with pre' = -log2(e)*pre already folded into weights:
//   sigmoid = rcp(1 + exp2(pre'))
// tanh(y) with y' = 2*log2(e)*y folded into weights:
//   tanh = 1 - 2*rcp(exp2(y') + 1)
__device__ __forceinline__ float sig_s(float pre_scaled) {
    return __builtin_amdgcn_rcpf(1.0f + __builtin_amdgcn_exp2f(pre_scaled));
}
__device__ __forceinline__ float tanh_s(float y_scaled) {
    return fmaf(-2.0f, __builtin_amdgcn_rcpf(__builtin_amdgcn_exp2f(y_scaled) + 1.0f), 1.0f);
}

__global__ __launch_bounds__(64, 1)
void mcgru_fused(const float* __restrict__ x,
                 const float* __restrict__ stat,
                 const float* __restrict__ demo_W,
                 const float* __restrict__ demo_b,
                 const float* __restrict__ lab_W,
                 const float* __restrict__ lab_b,
                 const float* __restrict__ Wih,
                 const float* __restrict__ bih,
                 const float* __restrict__ Whh,
                 const float* __restrict__ bhh,
                 const float* __restrict__ out_W,
                 const float* __restrict__ out_b,
                 float* __restrict__ out)
{
    const int b = blockIdx.x;
    const int l = threadIdx.x;   // one lab-chain per lane; block = 1 wave

    __shared__ float xs[2][CHUNK * LAB];     // 2 x 8 KB double-buffered x rows
    __shared__ float cat[HID + LAB * FF];

    const float S1 = -1.442695041f;   // -log2(e): r,z gates
    const float S2 =  2.885390082f;   // 2*log2(e): n gate

    // ---- per-lane (per-lab) weights into VGPRs ----
    float wl[LAB];
    #pragma unroll
    for (int k = 0; k < LAB; k += 4) {
        float4 v = *reinterpret_cast<const float4*>(lab_W + l * LAB + k);
        wl[k] = v.x; wl[k+1] = v.y; wl[k+2] = v.z; wl[k+3] = v.w;
    }
    float whh[48];
    #pragma unroll
    for (int k = 0; k < 48; k += 4) {
        float4 v = *reinterpret_cast<const float4*>(Whh + l * 48 + k);
        whh[k] = v.x; whh[k+1] = v.y; whh[k+2] = v.z; whh[k+3] = v.w;
    }
    float wih[12], bihv[12], bhhv[12];
    #pragma unroll
    for (int k = 0; k < 12; k += 4) {
        float4 a = *reinterpret_cast<const float4*>(Wih + l * 12 + k);
        float4 c = *reinterpret_cast<const float4*>(bih + l * 12 + k);
        float4 d = *reinterpret_cast<const float4*>(bhh + l * 12 + k);
        wih[k] = a.x; wih[k+1] = a.y; wih[k+2] = a.z; wih[k+3] = a.w;
        bihv[k] = c.x; bihv[k+1] = c.y; bihv[k+2] = c.z; bihv[k+3] = c.w;
        bhhv[k] = d.x; bhhv[k+1] = d.y; bhhv[k+2] = d.z; bhhv[k+3] = d.w;
    }
    // fold log2e scales into weights (r,z: S1; n: S2)
    float bc[8];
    #pragma unroll
    for (int g = 0; g < 8; ++g) {
        bc[g]  = S1 * (bihv[g] + bhhv[g]);
        wih[g] *= S1;
        #pragma unroll
        for (int k = 0; k < 4; ++k) whh[g*4 + k] *= S1;
    }
    #pragma unroll
    for (int g = 8; g < 12; ++g) {
        wih[g]  *= S2;
        bihv[g] *= S2;
        bhhv[g] *= S2;
        #pragma unroll
        for (int k = 0; k < 4; ++k) whh[g*4 + k] *= S2;
    }
    const float lb = lab_b[l];

    float h0 = 0.f, h1 = 0.f, h2 = 0.f, h3 = 0.f;

    const float4* xrow4 = reinterpret_cast<const float4*>(x + (size_t)b * TT * LAB);

    // ---- prologue: stage chunk 0 ----
    #pragma unroll
    for (int i = 0; i < 8; ++i) {
        float4 v = xrow4[i * 64 + l];
        *reinterpret_cast<float4*>(&xs[0][(i * 64 + l) * 4]) = v;
    }
    __syncthreads();

    for (int c = 0; c < NCHUNK; ++c) {
        const int cur = c & 1, nxt = cur ^ 1;
        const bool more = (c + 1 < NCHUNK);

        // T14 split: issue next chunk's global loads now, write to LDS at chunk end
        float4 stage[8];
        if (more) {
            const float4* src = xrow4 + (c + 1) * (CHUNK * LAB / 4);
            #pragma unroll
            for (int i = 0; i < 8; ++i) stage[i] = src[i * 64 + l];
        }

        // merged projection + GRU; unroll 2 so dot(t+1) fills GRU(t) stalls
        #pragma unroll 2
        for (int t = 0; t < CHUNK; ++t) {
            const float4* row = reinterpret_cast<const float4*>(&xs[cur][t * LAB]); // uniform -> broadcast
            float a0 = 0.f, a1 = 0.f, a2 = 0.f, a3 = 0.f;
            #pragma unroll
            for (int k = 0; k < LAB / 4; ++k) {
                float4 v = row[k];
                a0 = fmaf(v.x, wl[4*k + 0], a0);
                a1 = fmaf(v.y, wl[4*k + 1], a1);
                a2 = fmaf(v.z, wl[4*k + 2], a2);
                a3 = fmaf(v.w, wl[4*k + 3], a3);
            }
            const float xt = lb + ((a0 + a1) + (a2 + a3));

            float pre[8];
            #pragma unroll
            for (int g = 0; g < 8; ++g) {
                float acc = fmaf(xt, wih[g], bc[g]);
                acc = fmaf(h0, whh[g*4 + 0], acc);
                acc = fmaf(h1, whh[g*4 + 1], acc);
                acc = fmaf(h2, whh[g*4 + 2], acc);
                acc = fmaf(h3, whh[g*4 + 3], acc);
                pre[g] = acc;
            }
            const float r0 = sig_s(pre[0]);
            const float r1 = sig_s(pre[1]);
            const float r2 = sig_s(pre[2]);
            const float r3 = sig_s(pre[3]);
            const float z0 = sig_s(pre[4]);
            const float z1 = sig_s(pre[5]);
            const float z2 = sig_s(pre[6]);
            const float z3 = sig_s(pre[7]);

            float ghn[4], gin[4];
            #pragma unroll
            for (int i = 0; i < 4; ++i) {
                const int g = 8 + i;
                float acc = bhhv[g];
                acc = fmaf(h0, whh[g*4 + 0], acc);
                acc = fmaf(h1, whh[g*4 + 1], acc);
                acc = fmaf(h2, whh[g*4 + 2], acc);
                acc = fmaf(h3, whh[g*4 + 3], acc);
                ghn[i] = acc;
                gin[i] = fmaf(xt, wih[g], bihv[g]);
            }
            const float n0 = tanh_s(fmaf(r0, ghn[0], gin[0]));
            const float n1 = tanh_s(fmaf(r1, ghn[1], gin[1]));
            const float n2 = tanh_s(fmaf(r2, ghn[2], gin[2]));
            const float n3 = tanh_s(fmaf(r3, ghn[3], gin[3]));

            h0 = fmaf(z0, h0 - n0, n0);
            h1 = fmaf(z1, h1 - n1, n1);
            h2 = fmaf(z2, h2 - n2, n2);
            h3 = fmaf(z3, h3 - n3, n3);
        }

        if (more) {
            #pragma unroll
            for (int i = 0; i < 8; ++i)
                *reinterpret_cast<float4*>(&xs[nxt][(i * 64 + l) * 4]) = stage[i];
            __syncthreads();   // writes visible before next chunk's broadcast reads
        }
    }

    // ---- epilogue ----
    cat[HID + l*4 + 0] = h0;
    cat[HID + l*4 + 1] = h1;
    cat[HID + l*4 + 2] = h2;
    cat[HID + l*4 + 3] = h3;
    if (l < HID) {
        float acc = demo_b[l];
        const float* sr = stat + (size_t)b * DEMO;
        const float* dwr = demo_W + l * DEMO;
        #pragma unroll
        for (int d = 0; d < DEMO; ++d)
            acc = fmaf(sr[d], dwr[d], acc);
        cat[l] = acc;
    }
    __syncthreads();

    if (l < HID) {
        float acc = out_b[l];
        const float* wrow = out_W + l * (HID + LAB * FF);
        #pragma unroll
        for (int i = 0; i < HID + LAB * FF; i += 4) {
            float4 wv = *reinterpret_cast<const float4*>(wrow + i);
            acc = fmaf(cat[i + 0], wv.x, acc);
            acc = fmaf(cat[i + 1], wv.y, acc);
            acc = fmaf(cat[i + 2], wv.z, acc);
            acc = fmaf(cat[i + 3], wv.w, acc);
        }
        out[(size_t)b * HID + l] = acc;
    }
}

extern "C" void kernel_launch(void* const* d_in, const int* in_sizes, int n_in,
                              void* d_out, int out_size, void* d_ws, size_t ws_size,
                              hipStream_t stream) {
    const float* x      = (const float*)d_in[0];
    const float* stat   = (const float*)d_in[1];
    const float* demo_W = (const float*)d_in[2];
    const float* demo_b = (const float*)d_in[3];
    const float* lab_W  = (const float*)d_in[4];
    const float* lab_b  = (const float*)d_in[5];
    const float* Wih    = (const float*)d_in[6];
    const float* bih    = (const float*)d_in[7];
    const float* Whh    = (const float*)d_in[8];
    const float* bhh    = (const float*)d_in[9];
    const float* out_W  = (const float*)d_in[10];
    const float* out_b  = (const float*)d_in[11];
    float* out = (float*)d_out;

    dim3 grid(BSZ);
    dim3 block(LAB);
    hipLaunchKernelGGL(mcgru_fused, grid, block, 0, stream,
                       x, stat, demo_W, demo_b, lab_W, lab_b,
                       Wih, bih, Whh, bhh, out_W, out_b, out);
}